// Round 17
// baseline (496.863 us; speedup 1.0000x reference)
//
#include <hip/hip_runtime.h>

typedef _Float16 f16;
typedef _Float16 f16x8 __attribute__((ext_vector_type(8)));
typedef _Float16 f16x4 __attribute__((ext_vector_type(4)));
typedef _Float16 f16x2 __attribute__((ext_vector_type(2)));
typedef float f32x4 __attribute__((ext_vector_type(4)));

#define B_ 4
#define S_ 2048
#define DM 1024
#define NH 16
#define DK 64
#define DFF 4096

// Q pre-scale: fold 1/sqrt(dk)=0.125 and 1/ln2 into Q so softmax is exp2(s + C)
#define QSCALE 0.18033688011112042f
#define EXPC  -8.656170245333781f

__device__ __forceinline__ void async_copy16(const f16* g, f16* l) {
    __builtin_amdgcn_global_load_lds((const __attribute__((address_space(1))) void*)g,
                                     (__attribute__((address_space(3))) void*)l,
                                     16, 0, 0);
}

__device__ __forceinline__ f16x2 pk_cvt(float a, float b) {
    return __builtin_bit_cast(f16x2, __builtin_amdgcn_cvt_pkrtz(a, b));
}

// ------- fused fp32 -> f16 weight convert + bias concat + LN1 (merged) -------
__global__ __launch_bounds__(256) void convert_all(
        const float* __restrict__ wq, const float* __restrict__ wk,
        const float* __restrict__ wv, const float* __restrict__ wo,
        const float* __restrict__ w1, const float* __restrict__ w2,
        const float* __restrict__ bq, const float* __restrict__ bk,
        const float* __restrict__ bv,
        f16* __restrict__ wqkvb, f16* __restrict__ wob,
        f16* __restrict__ w1b, f16* __restrict__ w2b,
        float* __restrict__ bqkv,
        const float* __restrict__ x, f16* __restrict__ hbuf,
        const float* __restrict__ ln1a, const float* __restrict__ ln1b) {
    const int id = blockIdx.x;
    const int t = threadIdx.x;
    if (id >= 12300) {  // ---- LN1 path ----
        const int row = id - 12300;
        const float4 v = ((const float4*)(x + (size_t)row * DM))[t];
        float s1 = v.x + v.y + v.z + v.w;
        float s2 = v.x * v.x + v.y * v.y + v.z * v.z + v.w * v.w;
        #pragma unroll
        for (int off = 1; off < 64; off <<= 1) {
            s1 += __shfl_xor(s1, off);
            s2 += __shfl_xor(s2, off);
        }
        __shared__ float red[8];
        const int w = t >> 6, lane = t & 63;
        if (lane == 0) { red[w] = s1; red[4 + w] = s2; }
        __syncthreads();
        s1 = red[0] + red[1] + red[2] + red[3];
        s2 = red[4] + red[5] + red[6] + red[7];
        const float mean = s1 * (1.0f / DM);
        const float var = (s2 - s1 * mean) * (1.0f / (DM - 1));
        const float inv = ln1a[0] / (sqrtf(var) + 1e-5f);
        const float beta = ln1b[0];
        f16x4 o = { (f16)((v.x - mean) * inv + beta), (f16)((v.y - mean) * inv + beta),
                    (f16)((v.z - mean) * inv + beta), (f16)((v.w - mean) * inv + beta) };
        ((f16x4*)(hbuf + (size_t)row * DM))[t] = o;
        return;
    }
    const float* src; f16* dst; int base;
    if (id < 1024)      { src = wq; dst = wqkvb;               base = id; }
    else if (id < 2048) { src = wk; dst = wqkvb + 1024 * 1024; base = id - 1024; }
    else if (id < 3072) { src = wv; dst = wqkvb + 2048 * 1024; base = id - 2048; }
    else if (id < 4096) { src = wo; dst = wob;                 base = id - 3072; }
    else if (id < 8192) { src = w1; dst = w1b;                 base = id - 4096; }
    else if (id < 12288){ src = w2; dst = w2b;                 base = id - 8192; }
    else {
        const int i = (id - 12288) * 256 + t;
        if (i < 1024) bqkv[i] = bq[i];
        else if (i < 2048) bqkv[i] = bk[i - 1024];
        else if (i < 3072) bqkv[i] = bv[i - 2048];
        return;
    }
    const int i = base * 256 + t;
    float4 v = ((const float4*)src)[i];
    f16x4 o = { (f16)v.x, (f16)v.y, (f16)v.z, (f16)v.w };
    ((f16x4*)dst)[i] = o;
}

// ---------------- LayerNorm (torch: unbiased std, /(std+eps)) ----------------
__global__ __launch_bounds__(256) void ln_kernel(const float* __restrict__ x,
                                                 f16* __restrict__ out,
                                                 const float* __restrict__ alpha_p,
                                                 const float* __restrict__ beta_p) {
    const int row = blockIdx.x;
    const int t = threadIdx.x;
    const float4 v = ((const float4*)(x + (size_t)row * DM))[t];
    float s1 = v.x + v.y + v.z + v.w;
    float s2 = v.x * v.x + v.y * v.y + v.z * v.z + v.w * v.w;
    #pragma unroll
    for (int off = 1; off < 64; off <<= 1) {
        s1 += __shfl_xor(s1, off);
        s2 += __shfl_xor(s2, off);
    }
    __shared__ float red[8];
    const int w = t >> 6, lane = t & 63;
    if (lane == 0) { red[w] = s1; red[4 + w] = s2; }
    __syncthreads();
    s1 = red[0] + red[1] + red[2] + red[3];
    s2 = red[4] + red[5] + red[6] + red[7];
    const float mean = s1 * (1.0f / DM);
    const float var = (s2 - s1 * mean) * (1.0f / (DM - 1));
    const float inv = alpha_p[0] / (sqrtf(var) + 1e-5f);
    const float beta = beta_p[0];
    f16x4 o = { (f16)((v.x - mean) * inv + beta), (f16)((v.y - mean) * inv + beta),
                (f16)((v.z - mean) * inv + beta), (f16)((v.w - mean) * inv + beta) };
    ((f16x4*)(out + (size_t)row * DM))[t] = o;
}

// ---------------- GEMM: C[M,N] = A[M,K] @ B[N,K]^T + bias ----------------
// 2-phase m97-style pipeline (proven; ledger in git history R4-R13).
// MODE 0: f16 out; MODE 1: f16 relu out; MODE 2: f32 out + residual(f32)
// MODE 3: fused QKV epilogue (Q scaled, V transposed to vT[b,h,d,s])
template <int MODE, int BK = 32>
__global__ __launch_bounds__(256, 2) void gemm_bt(const f16* __restrict__ A,
                                                  const f16* __restrict__ B,
                                                  const float* __restrict__ bias,
                                                  const float* __restrict__ resid,
                                                  void* __restrict__ Cout,
                                                  f16* __restrict__ vT,
                                                  int M, int N, int K) {
    __shared__ __align__(16) f16 SMEM[4][128 * BK];
    const int t = threadIdx.x;
    const int lane = t & 63;
    const int w = t >> 6;
    const int quad = lane >> 4;
    const int l15 = lane & 15;
    const int wm = (w >> 1) * 64, wn = (w & 1) * 64;

    const int gx = gridDim.x;
    const int nwg = gx * gridDim.y;
    int lin = blockIdx.y * gx + blockIdx.x;
    lin = (lin & 7) * (nwg >> 3) + (lin >> 3);
    const int bm = (lin / gx) * 128, bn = (lin % gx) * 128;

    f32x4 acc[4][4];
    #pragma unroll
    for (int i = 0; i < 4; ++i)
        #pragma unroll
        for (int j = 0; j < 4; ++j)
            acc[i][j] = (f32x4){0.f, 0.f, 0.f, 0.f};

    int arow, csw;
    if constexpr (BK == 32) {
        arow = t >> 2;
        csw = ((t & 3) ^ ((arow >> 1) & 3)) * 8;
    } else {
        arow = t >> 3;
        csw = ((t & 7) ^ (arow & 7)) * 8;
    }
    const f16* Ag = A + (size_t)(bm + arow) * K + csw;
    const f16* Bg = B + (size_t)(bn + arow) * K + csw;
    const int wbase = (t & ~63) * 8;

    auto stage = [&](int ktile, int buf) {
        const f16* Agk = Ag + ktile * BK;
        const f16* Bgk = Bg + ktile * BK;
        if constexpr (BK == 32) {
            async_copy16(Agk,                  &SMEM[buf][wbase]);
            async_copy16(Agk + (size_t)64 * K, &SMEM[buf][2048 + wbase]);
            async_copy16(Bgk,                  &SMEM[2 + buf][wbase]);
            async_copy16(Bgk + (size_t)64 * K, &SMEM[2 + buf][2048 + wbase]);
        } else {
            #pragma unroll
            for (int g = 0; g < 4; ++g) {
                async_copy16(Agk + (size_t)(g * 32) * K, &SMEM[buf][g * 2048 + wbase]);
                async_copy16(Bgk + (size_t)(g * 32) * K, &SMEM[2 + buf][g * 2048 + wbase]);
            }
        }
    };

    stage(0, 0);
    __syncthreads();

    const int nkt = K / BK;
    for (int kt = 0; kt < nkt; ++kt) {
        const int cur = kt & 1;
        if (kt + 1 < nkt) stage(kt + 1, cur ^ 1);

        if constexpr (BK == 32) {
            f16x8 af[4], bf[4];
            #pragma unroll
            for (int mt = 0; mt < 4; ++mt) {
                const int r = wm + mt * 16 + l15;
                const int slot = quad ^ ((r >> 1) & 3);
                af[mt] = *(const f16x8*)&SMEM[cur][r * 32 + slot * 8];
            }
            #pragma unroll
            for (int nt = 0; nt < 4; ++nt) {
                const int r = wn + nt * 16 + l15;
                const int slot = quad ^ ((r >> 1) & 3);
                bf[nt] = *(const f16x8*)&SMEM[2 + cur][r * 32 + slot * 8];
            }
            #pragma unroll
            for (int mt = 0; mt < 4; ++mt)
                #pragma unroll
                for (int nt = 0; nt < 4; ++nt)
                    acc[mt][nt] = __builtin_amdgcn_mfma_f32_16x16x32_f16(af[mt], bf[nt], acc[mt][nt], 0, 0, 0);
        } else {
            #pragma unroll
            for (int half = 0; half < 2; ++half) {
                f16x8 af[4], bf[4];
                #pragma unroll
                for (int mt = 0; mt < 4; ++mt) {
                    const int r = wm + mt * 16 + l15;
                    const int slot = (quad + half * 4) ^ (r & 7);
                    af[mt] = *(const f16x8*)&SMEM[cur][r * 64 + slot * 8];
                }
                #pragma unroll
                for (int nt = 0; nt < 4; ++nt) {
                    const int r = wn + nt * 16 + l15;
                    const int slot = (quad + half * 4) ^ (r & 7);
                    bf[nt] = *(const f16x8*)&SMEM[2 + cur][r * 64 + slot * 8];
                }
                #pragma unroll
                for (int mt = 0; mt < 4; ++mt)
                    #pragma unroll
                    for (int nt = 0; nt < 4; ++nt)
                        acc[mt][nt] = __builtin_amdgcn_mfma_f32_16x16x32_f16(af[mt], bf[nt], acc[mt][nt], 0, 0, 0);
            }
        }

        __syncthreads();
    }

    const int r0 = bm + wm + (quad * 4);
    const int c0 = bn + wn + l15;

    if constexpr (MODE == 2) {
        #pragma unroll
        for (int mt = 0; mt < 4; ++mt)
            #pragma unroll
            for (int nt = 0; nt < 4; ++nt) {
                const int col = c0 + nt * 16;
                const float bv = bias[col];
                #pragma unroll
                for (int i = 0; i < 4; ++i) {
                    const int row = r0 + mt * 16 + i;
                    ((float*)Cout)[(size_t)row * N + col] =
                        acc[mt][nt][i] + bv + resid[(size_t)row * N + col];
                }
            }
        return;
    }

    if (MODE == 3 && bn >= 2048) {
        #pragma unroll
        for (int mt = 0; mt < 4; ++mt)
            #pragma unroll
            for (int nt = 0; nt < 4; ++nt) {
                const int col = c0 + nt * 16;
                const float bv = bias[col];
                const int h = (col >> 6) & 15;
                const int d = col & 63;
                const int rowb = r0 + mt * 16;
                const int b = rowb >> 11, s = rowb & 2047;
                f16x4 pk;
                #pragma unroll
                for (int i = 0; i < 4; ++i) pk[i] = (f16)(acc[mt][nt][i] + bv);
                *(f16x4*)&vT[(size_t)(((b << 4) + h) * 64 + d) * 2048 + s] = pk;
            }
        return;
    }

    // f16 outputs: LDS-staged epilogue (full-line f16x8 stores; avoids RFO)
    static_assert(BK == 64 || MODE == 2, "LDS epilogue sized for BK=64");
    {
        constexpr int CST = 136;
        f16* Cs = &SMEM[0][0];
        const float qs = (MODE == 3 && bn < 1024) ? QSCALE : 1.f;
        #pragma unroll
        for (int mt = 0; mt < 4; ++mt)
            #pragma unroll
            for (int nt = 0; nt < 4; ++nt) {
                const int lcol = wn + nt * 16 + l15;
                const float bv = bias[bn + lcol];
                #pragma unroll
                for (int i = 0; i < 4; ++i) {
                    const int lrow = wm + mt * 16 + quad * 4 + i;
                    float v = acc[mt][nt][i] + bv;
                    if (MODE == 1) v = v > 0.f ? v : 0.f;
                    Cs[lrow * CST + lcol] = (f16)(v * qs);
                }
            }
        __syncthreads();
        #pragma unroll
        for (int k = 0; k < 8; ++k) {
            const int e = t * 8 + k * 2048;
            const int row = e >> 7, colg = e & 127;
            const f16x8 vv = *(const f16x8*)&Cs[row * CST + colg];
            *(f16x8*)&((f16*)Cout)[(size_t)(bm + row) * N + bn + colg] = vv;
        }
    }
}

// -------- 8-phase counted-vmcnt GEMM, 256x256 tile (T3+T4, proven R16) ------
// ALL 8 half-tiles of kt+1 issued at ph0/ph1 in consumption order:
//   GATE1 (after ph1): vmcnt(8) -- retires A13(kt) (~4 phases old).
//   GATE2 (after ph3): vmcnt(2) -- retires B0-3+A0,A2(kt+1); keeps A13(kt+1)
//                                  in flight across the iteration boundary.
// LDS = 65536 f16 = 128KB: A dbuf [0,32768), B dbuf [32768,65536).
// 512 thr / 8 waves (2M x 4N), BK=64, 1 block/CU.
// MODE 1: relu f16 out (FFN1).  MODE 3: QKV fused epilogue -- tiles are
// 256-col aligned so each block is wholly Q (<1024, scaled), K, or V (>=2048,
// transposed f16x4 stores to vT[b,h,d,s]); Q/K go through the LDS-staged
// full-line path (SM is dead post-loop; 256x256 f16 fits exactly).
template <int MODE>
__global__ __launch_bounds__(512, 2) void gemm_8ph(const f16* __restrict__ A,
                                                   const f16* __restrict__ B,
                                                   const float* __restrict__ bias,
                                                   f16* __restrict__ Cout,
                                                   f16* __restrict__ vT,
                                                   int M, int N, int K) {
    __shared__ __align__(16) f16 SM[65536];    // 128KB
    const int t = threadIdx.x;
    const int lane = t & 63, w = t >> 6;
    const int quad = lane >> 4, l15 = lane & 15;
    const int wm = (w >> 2) * 128, wn = (w & 3) * 64;

    const int gx = gridDim.x;                  // N/256
    const int nwg = gx * gridDim.y;
    int lin = blockIdx.y * gx + blockIdx.x;
    lin = (lin & 7) * (nwg >> 3) + (lin >> 3);
    const int bm = (lin / gx) * 256, bn = (lin % gx) * 256;

    f32x4 acc[8][4];
    #pragma unroll
    for (int i = 0; i < 8; ++i)
        #pragma unroll
        for (int j = 0; j < 4; ++j)
            acc[i][j] = (f32x4){0.f, 0.f, 0.f, 0.f};

    const int rt = t >> 3;                     // 0..63
    const int csw = ((t & 7) ^ (rt & 7)) * 8;  // pre-swizzled source chunk
    const f16* Ag = A + (size_t)(bm + rt) * K + csw;
    const f16* Bg = B + (size_t)(bn + rt) * K + csw;
    const int wb8 = (t & ~63) * 8;             // wave-uniform LDS dest base

    // stage one 64-row piece (hh) of A or B for K-tile kt into buf kt&1
    auto issue = [&](int kt, int hh, int isB) {
        const f16* g = (isB ? Bg : Ag) + (size_t)(hh * 64) * K + kt * 64;
        f16* d = &SM[(isB ? 32768 : 0) + (kt & 1) * 16384 + hh * 4096 + wb8];
        async_copy16(g, d);
    };

    auto phase = [&](int cb, int mh, int nh) {
        f16x8 af[4][2], bf[2][2];
        #pragma unroll
        for (int mt = 0; mt < 4; ++mt) {
            const int r = wm + mh * 64 + mt * 16 + l15;
            #pragma unroll
            for (int kp = 0; kp < 2; ++kp) {
                const int slot = (quad + kp * 4) ^ (r & 7);
                af[mt][kp] = *(const f16x8*)&SM[cb * 16384 + r * 64 + slot * 8];
            }
        }
        #pragma unroll
        for (int nf = 0; nf < 2; ++nf) {
            const int r = wn + nh * 32 + nf * 16 + l15;
            #pragma unroll
            for (int kp = 0; kp < 2; ++kp) {
                const int slot = (quad + kp * 4) ^ (r & 7);
                bf[nf][kp] = *(const f16x8*)&SM[32768 + cb * 16384 + r * 64 + slot * 8];
            }
        }
        __builtin_amdgcn_s_setprio(1);
        #pragma unroll
        for (int mt = 0; mt < 4; ++mt)
            #pragma unroll
            for (int nf = 0; nf < 2; ++nf)
                #pragma unroll
                for (int kp = 0; kp < 2; ++kp)
                    acc[mh * 4 + mt][nh * 2 + nf] = __builtin_amdgcn_mfma_f32_16x16x32_f16(
                        af[mt][kp], bf[nf][kp], acc[mh * 4 + mt][nh * 2 + nf], 0, 0, 0);
        __builtin_amdgcn_s_setprio(0);
    };

    // prologue: full tile 0, drained
    #pragma unroll
    for (int hh = 0; hh < 4; ++hh) issue(0, hh, 1);
    #pragma unroll
    for (int hh = 0; hh < 4; ++hh) issue(0, hh, 0);
    asm volatile("s_waitcnt vmcnt(0)" ::: "memory");
    __builtin_amdgcn_s_barrier();
    asm volatile("" ::: "memory");

    const int nkt = K >> 6;
    for (int kt = 0; kt < nkt; ++kt) {
        const int cb = kt & 1;
        const bool pf = (kt + 1 < nkt);
        // ph0: issue first half of tile kt+1 (consumption order: B first, A02)
        if (pf) { issue(kt + 1, 0, 1); issue(kt + 1, 1, 1);
                  issue(kt + 1, 0, 0); issue(kt + 1, 2, 0); }
        phase(cb, 0, 0);
        // ph1: issue second half (B23, A13)
        if (pf) { issue(kt + 1, 2, 1); issue(kt + 1, 3, 1);
                  issue(kt + 1, 1, 0); issue(kt + 1, 3, 0); }
        phase(cb, 0, 1);
        // GATE1: retire A13(kt) (issued iter kt-1 ph1, ~4 phases old)
        if (pf) asm volatile("s_waitcnt vmcnt(8)" ::: "memory");
        else    asm volatile("s_waitcnt vmcnt(0)" ::: "memory");
        __builtin_amdgcn_s_barrier();
        asm volatile("" ::: "memory");
        phase(cb, 1, 0);
        phase(cb, 1, 1);
        // GATE2: retire B0-3 + A0,A2 of (kt+1); keep A13(kt+1) in flight
        if (pf) asm volatile("s_waitcnt vmcnt(2)" ::: "memory");
        __builtin_amdgcn_s_barrier();
        asm volatile("" ::: "memory");
    }

    // V epilogue (MODE 3, bn >= 2048): packed f16x4 transposed stores
    if (MODE == 3 && bn >= 2048) {
        #pragma unroll
        for (int am = 0; am < 8; ++am) {
            const int rowb = bm + wm + (am >> 2) * 64 + (am & 3) * 16 + quad * 4;
            const int b = rowb >> 11, s = rowb & 2047;
            #pragma unroll
            for (int an = 0; an < 4; ++an) {
                const int col = bn + wn + (an >> 1) * 32 + (an & 1) * 16 + l15;
                const float bv = bias[col];
                const int h = (col >> 6) & 15;
                const int d = col & 63;
                f16x4 pk;
                #pragma unroll
                for (int i = 0; i < 4; ++i) pk[i] = (f16)(acc[am][an][i] + bv);
                *(f16x4*)&vT[(size_t)(((b << 4) + h) * 64 + d) * 2048 + s] = pk;
            }
        }
        return;
    }

    // f16 epilogue (MODE 1 relu; MODE 3 Q/K): LDS-staged full-line stores
    {
        const float qs = (MODE == 3 && bn < 1024) ? QSCALE : 1.f;
        #pragma unroll
        for (int am = 0; am < 8; ++am) {
            const int lrow = wm + (am >> 2) * 64 + (am & 3) * 16 + quad * 4;
            #pragma unroll
            for (int an = 0; an < 4; ++an) {
                const int lcol = wn + (an >> 1) * 32 + (an & 1) * 16 + l15;
                const float bv = bias[bn + lcol];
                #pragma unroll
                for (int i = 0; i < 4; ++i) {
                    float v = acc[am][an][i] + bv;
                    if (MODE == 1) v = v > 0.f ? v : 0.f;
                    SM[(lrow + i) * 256 + lcol] = (f16)(v * qs);
                }
            }
        }
        __syncthreads();
        #pragma unroll
        for (int k = 0; k < 16; ++k) {
            const int e = t * 8 + k * 4096;
            const int row = e >> 8, col = e & 255;
            *(f16x8*)&Cout[(size_t)(bm + row) * N + bn + col] = *(const f16x8*)&SM[e];
        }
    }
}

// ---------------- Flash attention: P stays in registers ----------------
// [R16 audit: ~77 GFLOP / 91us = 0.84 PF; MfmaUtil 57 + VALU 43 = issue-bound;
//  half the MFMAs are half-rate 16x16x16 -- next lever is a P-layout transform
//  to 16x16x32 PV (cross-lane), deferred as high-risk.]
__global__ __launch_bounds__(256, 4) void attn_kernel(const f16* __restrict__ qkv,
                                                      const f16* __restrict__ vT,
                                                      f16* __restrict__ ctx) {
    const int lin = blockIdx.y * 16 + blockIdx.x;
    const int xcd = lin & 7, idx = lin >> 3;
    const int bh = (idx >> 4) * 8 + xcd;          // xcd = bh % 8
    const int q0 = (idx & 15) * 128;
    const int b = bh >> 4, h = bh & 15;
    const int t = threadIdx.x, lane = t & 63, w = t >> 6;
    const int quad = lane >> 4, l15 = lane & 15;
    const int e = l15 & 7;

    __shared__ __align__(16) f16 KV[4][64 * 64];

    const int srow = t >> 3;
    const int scS = ((t & 7) ^ (srow & 7)) * 8;

    const f16* Kg = qkv + (size_t)(b * S_ + srow) * 3072 + 1024 + h * 64 + scS;
    const f16* Vg = vT + (size_t)(bh * 64 + srow) * S_ + scS;
    const int wb8 = (t & ~63) * 8;

    {
        const f16* g = qkv + (size_t)(b * S_ + q0 + srow) * 3072 + h * 64 + scS;
        f16* dst = &KV[0][wb8];
        #pragma unroll
        for (int c = 0; c < 4; ++c)
            async_copy16(g + (size_t)(c * 32) * 3072, dst + c * 2048);
    }
    __syncthreads();

    f16x8 qf[2][2];
    #pragma unroll
    for (int band = 0; band < 2; ++band) {
        const int qr = w * 32 + band * 16 + l15;
        const int qx = qr & 7;
        qf[band][0] = *(const f16x8*)&KV[0][qr * 64 + ((quad) ^ qx) * 8];
        qf[band][1] = *(const f16x8*)&KV[0][qr * 64 + ((quad + 4) ^ qx) * 8];
    }
    __syncthreads();

    {
        async_copy16(Kg, &KV[0][wb8]);
        async_copy16(Kg + (size_t)32 * 3072, &KV[0][2048 + wb8]);
        async_copy16(Vg, &KV[2][wb8]);
        async_copy16(Vg + (size_t)32 * S_, &KV[2][2048 + wb8]);
    }
    __syncthreads();

    const int kbase0 = l15 * 64 + ((quad) ^ e) * 8;
    const int kbase1 = l15 * 64 + ((quad + 4) ^ e) * 8;
    int vbase[4];
    #pragma unroll
    for (int kb = 0; kb < 4; ++kb)
        vbase[kb] = l15 * 64 + (((kb * 2) + (quad >> 1)) ^ e) * 8 + (quad & 1) * 4;

    const f16 one = (f16)1.f;
    const f16x4 ones4 = { one, one, one, one };
    const f32x4 einit = (f32x4){EXPC, EXPC, EXPC, EXPC};

    f32x4 o[2][4];
    f32x4 accl[2];
    #pragma unroll
    for (int band = 0; band < 2; ++band) {
        accl[band] = (f32x4){0.f, 0.f, 0.f, 0.f};
        #pragma unroll
        for (int dt = 0; dt < 4; ++dt) o[band][dt] = (f32x4){0.f, 0.f, 0.f, 0.f};
    }

    for (int j = 0; j < 32; ++j) {
        const int cur = j & 1;
        if (j + 1 < 32) {
            const int nxt = cur ^ 1;
            const f16* kg = Kg + (size_t)(j + 1) * 64 * 3072;
            async_copy16(kg, &KV[nxt][wb8]);
            async_copy16(kg + (size_t)32 * 3072, &KV[nxt][2048 + wb8]);
            const f16* vg = Vg + (j + 1) * 64;
            async_copy16(vg, &KV[2 + nxt][wb8]);
            async_copy16(vg + (size_t)32 * S_, &KV[2 + nxt][2048 + wb8]);
        }

        f16x4 pa[2][4];
        #pragma unroll
        for (int band = 0; band < 2; ++band) {
            #pragma unroll
            for (int nt = 0; nt < 4; ++nt) {
                const f16x8 kf0 = *(const f16x8*)&KV[cur][kbase0 + nt * 1024];
                const f16x8 kf1 = *(const f16x8*)&KV[cur][kbase1 + nt * 1024];
                f32x4 s = einit;
                s = __builtin_amdgcn_mfma_f32_16x16x32_f16(kf0, qf[band][0], s, 0, 0, 0);
                s = __builtin_amdgcn_mfma_f32_16x16x32_f16(kf1, qf[band][1], s, 0, 0, 0);
                const f16x2 lo = pk_cvt(__builtin_amdgcn_exp2f(s[0]),
                                        __builtin_amdgcn_exp2f(s[1]));
                const f16x2 hi = pk_cvt(__builtin_amdgcn_exp2f(s[2]),
                                        __builtin_amdgcn_exp2f(s[3]));
                const f16x4 p = __builtin_shufflevector(lo, hi, 0, 1, 2, 3);
                pa[band][nt] = p;
                accl[band] = __builtin_amdgcn_mfma_f32_16x16x16f16(p, ones4, accl[band], 0, 0, 0);
            }
        }

        __builtin_amdgcn_s_setprio(1);
        #pragma unroll
        for (int dt = 0; dt < 4; ++dt) {
            #pragma unroll
            for (int kb = 0; kb < 4; ++kb) {
                const f16x4 vf = *(const f16x4*)&KV[2 + cur][vbase[kb] + dt * 1024];
                o[0][dt] = __builtin_amdgcn_mfma_f32_16x16x16f16(pa[0][kb], vf, o[0][dt], 0, 0, 0);
                o[1][dt] = __builtin_amdgcn_mfma_f32_16x16x16f16(pa[1][kb], vf, o[1][dt], 0, 0, 0);
            }
        }
        __builtin_amdgcn_s_setprio(0);

        __syncthreads();
    }

    #pragma unroll
    for (int band = 0; band < 2; ++band) {
        float linv[4];
        #pragma unroll
        for (int i = 0; i < 4; ++i) linv[i] = 1.f / accl[band][i];
        #pragma unroll
        for (int dt = 0; dt < 4; ++dt)
            #pragma unroll
            for (int i = 0; i < 4; ++i) {
                const int r = q0 + w * 32 + band * 16 + quad * 4 + i;
                const int d = dt * 16 + l15;
                ctx[(size_t)(b * S_ + r) * DM + h * 64 + d] = (f16)(o[band][dt][i] * linv[i]);
            }
    }
}

// ---------------- launch ----------------
extern "C" void kernel_launch(void* const* d_in, const int* in_sizes, int n_in,
                              void* d_out, int out_size, void* d_ws, size_t ws_size,
                              hipStream_t stream) {
    const float* x    = (const float*)d_in[0];
    const float* wq   = (const float*)d_in[2];
    const float* bq   = (const float*)d_in[3];
    const float* wk   = (const float*)d_in[4];
    const float* bk   = (const float*)d_in[5];
    const float* wv   = (const float*)d_in[6];
    const float* bv   = (const float*)d_in[7];
    const float* wo   = (const float*)d_in[8];
    const float* bo   = (const float*)d_in[9];
    const float* w1   = (const float*)d_in[10];
    const float* b1   = (const float*)d_in[11];
    const float* w2   = (const float*)d_in[12];
    const float* b2   = (const float*)d_in[13];
    const float* ln1a = (const float*)d_in[14];
    const float* ln1b = (const float*)d_in[15];
    const float* ln2a = (const float*)d_in[16];
    const float* ln2b = (const float*)d_in[17];
    float* out = (float*)d_out;

    char* ws = (char*)d_ws;
    size_t off = 0;
    auto alloc = [&](size_t bytes) -> void* {
        void* p = ws + off;
        off += (bytes + 255) & ~(size_t)255;
        return p;
    };
    f16* wqkvb  = (f16*)alloc((size_t)3072 * 1024 * 2);
    f16* wob    = (f16*)alloc((size_t)1024 * 1024 * 2);
    f16* w1b    = (f16*)alloc((size_t)4096 * 1024 * 2);
    f16* w2b    = (f16*)alloc((size_t)1024 * 4096 * 2);
    float* bqkv = (float*)alloc((size_t)3072 * 4);
    f16* hbuf   = (f16*)alloc((size_t)8192 * 1024 * 2);
    f16* qkvb   = (f16*)alloc((size_t)8192 * 3072 * 2);
    f16* vTb    = (f16*)alloc((size_t)64 * 64 * 2048 * 2);
    f16* ctxb   = (f16*)alloc((size_t)8192 * 1024 * 2);
    f16* ffn1b  = qkvb;  // overlay: qkv (48MB) + vT (16MB) region, both dead by FFN1

    const int M = B_ * S_;  // 8192

    convert_all<<<12300 + M, 256, 0, stream>>>(wq, wk, wv, wo, w1, w2, bq, bk, bv,
                                               wqkvb, wob, w1b, w2b, bqkv,
                                               x, hbuf, ln1a, ln1b);
    // QKV: 8-phase counted-vmcnt 256x256 kernel (fused Q-scale/K/V-transpose)
    gemm_8ph<3><<<dim3(3072 / 256, M / 256), 512, 0, stream>>>(hbuf, wqkvb, bqkv, qkvb, vTb, M, 3072, 1024);
    attn_kernel<<<dim3(16, 64), 256, 0, stream>>>(qkvb, vTb, ctxb);
    gemm_bt<2, 64><<<dim3(1024 / 128, M / 128), 256, 0, stream>>>(ctxb, wob, bo, x, out, nullptr, M, 1024, 1024);
    ln_kernel<<<M, 256, 0, stream>>>(out, hbuf, ln2a, ln2b);
    // FFN1: 8-phase counted-vmcnt 256x256 kernel (relu f16 out)
    gemm_8ph<1><<<dim3(4096 / 256, M / 256), 512, 0, stream>>>(hbuf, w1b, b1, ffn1b, nullptr, M, 4096, 1024);
    gemm_bt<2, 64><<<dim3(1024 / 128, M / 128), 256, 0, stream>>>(ffn1b, w2b, b2, out, out, nullptr, M, 1024, 4096);
}

// Round 18
// 486.173 us; speedup vs baseline: 1.0220x; 1.0220x over previous
//
#include <hip/hip_runtime.h>

typedef _Float16 f16;
typedef _Float16 f16x8 __attribute__((ext_vector_type(8)));
typedef _Float16 f16x4 __attribute__((ext_vector_type(4)));
typedef _Float16 f16x2 __attribute__((ext_vector_type(2)));
typedef float f32x4 __attribute__((ext_vector_type(4)));

#define B_ 4
#define S_ 2048
#define DM 1024
#define NH 16
#define DK 64
#define DFF 4096

// Q pre-scale: fold 1/sqrt(dk)=0.125 and 1/ln2 into Q so softmax is exp2(s + C)
#define QSCALE 0.18033688011112042f
#define EXPC  -8.656170245333781f

__device__ __forceinline__ void async_copy16(const f16* g, f16* l) {
    __builtin_amdgcn_global_load_lds((const __attribute__((address_space(1))) void*)g,
                                     (__attribute__((address_space(3))) void*)l,
                                     16, 0, 0);
}

__device__ __forceinline__ f16x2 pk_cvt(float a, float b) {
    return __builtin_bit_cast(f16x2, __builtin_amdgcn_cvt_pkrtz(a, b));
}

// ------- fused fp32 -> f16 weight convert + bias concat + LN1 (merged) -------
__global__ __launch_bounds__(256) void convert_all(
        const float* __restrict__ wq, const float* __restrict__ wk,
        const float* __restrict__ wv, const float* __restrict__ wo,
        const float* __restrict__ w1, const float* __restrict__ w2,
        const float* __restrict__ bq, const float* __restrict__ bk,
        const float* __restrict__ bv,
        f16* __restrict__ wqkvb, f16* __restrict__ wob,
        f16* __restrict__ w1b, f16* __restrict__ w2b,
        float* __restrict__ bqkv,
        const float* __restrict__ x, f16* __restrict__ hbuf,
        const float* __restrict__ ln1a, const float* __restrict__ ln1b) {
    const int id = blockIdx.x;
    const int t = threadIdx.x;
    if (id >= 12300) {  // ---- LN1 path ----
        const int row = id - 12300;
        const float4 v = ((const float4*)(x + (size_t)row * DM))[t];
        float s1 = v.x + v.y + v.z + v.w;
        float s2 = v.x * v.x + v.y * v.y + v.z * v.z + v.w * v.w;
        #pragma unroll
        for (int off = 1; off < 64; off <<= 1) {
            s1 += __shfl_xor(s1, off);
            s2 += __shfl_xor(s2, off);
        }
        __shared__ float red[8];
        const int w = t >> 6, lane = t & 63;
        if (lane == 0) { red[w] = s1; red[4 + w] = s2; }
        __syncthreads();
        s1 = red[0] + red[1] + red[2] + red[3];
        s2 = red[4] + red[5] + red[6] + red[7];
        const float mean = s1 * (1.0f / DM);
        const float var = (s2 - s1 * mean) * (1.0f / (DM - 1));
        const float inv = ln1a[0] / (sqrtf(var) + 1e-5f);
        const float beta = ln1b[0];
        f16x4 o = { (f16)((v.x - mean) * inv + beta), (f16)((v.y - mean) * inv + beta),
                    (f16)((v.z - mean) * inv + beta), (f16)((v.w - mean) * inv + beta) };
        ((f16x4*)(hbuf + (size_t)row * DM))[t] = o;
        return;
    }
    const float* src; f16* dst; int base;
    if (id < 1024)      { src = wq; dst = wqkvb;               base = id; }
    else if (id < 2048) { src = wk; dst = wqkvb + 1024 * 1024; base = id - 1024; }
    else if (id < 3072) { src = wv; dst = wqkvb + 2048 * 1024; base = id - 2048; }
    else if (id < 4096) { src = wo; dst = wob;                 base = id - 3072; }
    else if (id < 8192) { src = w1; dst = w1b;                 base = id - 4096; }
    else if (id < 12288){ src = w2; dst = w2b;                 base = id - 8192; }
    else {
        const int i = (id - 12288) * 256 + t;
        if (i < 1024) bqkv[i] = bq[i];
        else if (i < 2048) bqkv[i] = bk[i - 1024];
        else if (i < 3072) bqkv[i] = bv[i - 2048];
        return;
    }
    const int i = base * 256 + t;
    float4 v = ((const float4*)src)[i];
    f16x4 o = { (f16)v.x, (f16)v.y, (f16)v.z, (f16)v.w };
    ((f16x4*)dst)[i] = o;
}

// ---------------- LayerNorm (torch: unbiased std, /(std+eps)) ----------------
__global__ __launch_bounds__(256) void ln_kernel(const float* __restrict__ x,
                                                 f16* __restrict__ out,
                                                 const float* __restrict__ alpha_p,
                                                 const float* __restrict__ beta_p) {
    const int row = blockIdx.x;
    const int t = threadIdx.x;
    const float4 v = ((const float4*)(x + (size_t)row * DM))[t];
    float s1 = v.x + v.y + v.z + v.w;
    float s2 = v.x * v.x + v.y * v.y + v.z * v.z + v.w * v.w;
    #pragma unroll
    for (int off = 1; off < 64; off <<= 1) {
        s1 += __shfl_xor(s1, off);
        s2 += __shfl_xor(s2, off);
    }
    __shared__ float red[8];
    const int w = t >> 6, lane = t & 63;
    if (lane == 0) { red[w] = s1; red[4 + w] = s2; }
    __syncthreads();
    s1 = red[0] + red[1] + red[2] + red[3];
    s2 = red[4] + red[5] + red[6] + red[7];
    const float mean = s1 * (1.0f / DM);
    const float var = (s2 - s1 * mean) * (1.0f / (DM - 1));
    const float inv = alpha_p[0] / (sqrtf(var) + 1e-5f);
    const float beta = beta_p[0];
    f16x4 o = { (f16)((v.x - mean) * inv + beta), (f16)((v.y - mean) * inv + beta),
                (f16)((v.z - mean) * inv + beta), (f16)((v.w - mean) * inv + beta) };
    ((f16x4*)(out + (size_t)row * DM))[t] = o;
}

// ---------------- GEMM: C[M,N] = A[M,K] @ B[N,K]^T + bias ----------------
// 2-phase m97-style pipeline (proven; ledger in git history R4-R13).
// MODE 0: f16 out; MODE 1: f16 relu out; MODE 2: f32 out + residual(f32)
// MODE 3: fused QKV epilogue (Q scaled, V transposed to vT[b,h,d,s])
// [R17: QKV on gemm_8ph REGRESSED +28us -- 384-block grid = 1.5 rounds at
//  1 blk/CU wastes 33% of machine; 8-phase only pays on clean-packing grids
//  (FFN1: 512 blocks = 2 rounds). QKV reverted to this kernel.]
template <int MODE, int BK = 32>
__global__ __launch_bounds__(256, 2) void gemm_bt(const f16* __restrict__ A,
                                                  const f16* __restrict__ B,
                                                  const float* __restrict__ bias,
                                                  const float* __restrict__ resid,
                                                  void* __restrict__ Cout,
                                                  f16* __restrict__ vT,
                                                  int M, int N, int K) {
    __shared__ __align__(16) f16 SMEM[4][128 * BK];
    const int t = threadIdx.x;
    const int lane = t & 63;
    const int w = t >> 6;
    const int quad = lane >> 4;
    const int l15 = lane & 15;
    const int wm = (w >> 1) * 64, wn = (w & 1) * 64;

    const int gx = gridDim.x;
    const int nwg = gx * gridDim.y;
    int lin = blockIdx.y * gx + blockIdx.x;
    lin = (lin & 7) * (nwg >> 3) + (lin >> 3);
    const int bm = (lin / gx) * 128, bn = (lin % gx) * 128;

    f32x4 acc[4][4];
    #pragma unroll
    for (int i = 0; i < 4; ++i)
        #pragma unroll
        for (int j = 0; j < 4; ++j)
            acc[i][j] = (f32x4){0.f, 0.f, 0.f, 0.f};

    int arow, csw;
    if constexpr (BK == 32) {
        arow = t >> 2;
        csw = ((t & 3) ^ ((arow >> 1) & 3)) * 8;
    } else {
        arow = t >> 3;
        csw = ((t & 7) ^ (arow & 7)) * 8;
    }
    const f16* Ag = A + (size_t)(bm + arow) * K + csw;
    const f16* Bg = B + (size_t)(bn + arow) * K + csw;
    const int wbase = (t & ~63) * 8;

    auto stage = [&](int ktile, int buf) {
        const f16* Agk = Ag + ktile * BK;
        const f16* Bgk = Bg + ktile * BK;
        if constexpr (BK == 32) {
            async_copy16(Agk,                  &SMEM[buf][wbase]);
            async_copy16(Agk + (size_t)64 * K, &SMEM[buf][2048 + wbase]);
            async_copy16(Bgk,                  &SMEM[2 + buf][wbase]);
            async_copy16(Bgk + (size_t)64 * K, &SMEM[2 + buf][2048 + wbase]);
        } else {
            #pragma unroll
            for (int g = 0; g < 4; ++g) {
                async_copy16(Agk + (size_t)(g * 32) * K, &SMEM[buf][g * 2048 + wbase]);
                async_copy16(Bgk + (size_t)(g * 32) * K, &SMEM[2 + buf][g * 2048 + wbase]);
            }
        }
    };

    stage(0, 0);
    __syncthreads();

    const int nkt = K / BK;
    for (int kt = 0; kt < nkt; ++kt) {
        const int cur = kt & 1;
        if (kt + 1 < nkt) stage(kt + 1, cur ^ 1);

        if constexpr (BK == 32) {
            f16x8 af[4], bf[4];
            #pragma unroll
            for (int mt = 0; mt < 4; ++mt) {
                const int r = wm + mt * 16 + l15;
                const int slot = quad ^ ((r >> 1) & 3);
                af[mt] = *(const f16x8*)&SMEM[cur][r * 32 + slot * 8];
            }
            #pragma unroll
            for (int nt = 0; nt < 4; ++nt) {
                const int r = wn + nt * 16 + l15;
                const int slot = quad ^ ((r >> 1) & 3);
                bf[nt] = *(const f16x8*)&SMEM[2 + cur][r * 32 + slot * 8];
            }
            #pragma unroll
            for (int mt = 0; mt < 4; ++mt)
                #pragma unroll
                for (int nt = 0; nt < 4; ++nt)
                    acc[mt][nt] = __builtin_amdgcn_mfma_f32_16x16x32_f16(af[mt], bf[nt], acc[mt][nt], 0, 0, 0);
        } else {
            #pragma unroll
            for (int half = 0; half < 2; ++half) {
                f16x8 af[4], bf[4];
                #pragma unroll
                for (int mt = 0; mt < 4; ++mt) {
                    const int r = wm + mt * 16 + l15;
                    const int slot = (quad + half * 4) ^ (r & 7);
                    af[mt] = *(const f16x8*)&SMEM[cur][r * 64 + slot * 8];
                }
                #pragma unroll
                for (int nt = 0; nt < 4; ++nt) {
                    const int r = wn + nt * 16 + l15;
                    const int slot = (quad + half * 4) ^ (r & 7);
                    bf[nt] = *(const f16x8*)&SMEM[2 + cur][r * 64 + slot * 8];
                }
                #pragma unroll
                for (int mt = 0; mt < 4; ++mt)
                    #pragma unroll
                    for (int nt = 0; nt < 4; ++nt)
                        acc[mt][nt] = __builtin_amdgcn_mfma_f32_16x16x32_f16(af[mt], bf[nt], acc[mt][nt], 0, 0, 0);
            }
        }

        __syncthreads();
    }

    const int r0 = bm + wm + (quad * 4);
    const int c0 = bn + wn + l15;

    if constexpr (MODE == 2) {
        #pragma unroll
        for (int mt = 0; mt < 4; ++mt)
            #pragma unroll
            for (int nt = 0; nt < 4; ++nt) {
                const int col = c0 + nt * 16;
                const float bv = bias[col];
                #pragma unroll
                for (int i = 0; i < 4; ++i) {
                    const int row = r0 + mt * 16 + i;
                    ((float*)Cout)[(size_t)row * N + col] =
                        acc[mt][nt][i] + bv + resid[(size_t)row * N + col];
                }
            }
        return;
    }

    if (MODE == 3 && bn >= 2048) {
        #pragma unroll
        for (int mt = 0; mt < 4; ++mt)
            #pragma unroll
            for (int nt = 0; nt < 4; ++nt) {
                const int col = c0 + nt * 16;
                const float bv = bias[col];
                const int h = (col >> 6) & 15;
                const int d = col & 63;
                const int rowb = r0 + mt * 16;
                const int b = rowb >> 11, s = rowb & 2047;
                f16x4 pk;
                #pragma unroll
                for (int i = 0; i < 4; ++i) pk[i] = (f16)(acc[mt][nt][i] + bv);
                *(f16x4*)&vT[(size_t)(((b << 4) + h) * 64 + d) * 2048 + s] = pk;
            }
        return;
    }

    // f16 outputs: LDS-staged epilogue (full-line f16x8 stores; avoids RFO)
    static_assert(BK == 64 || MODE == 2, "LDS epilogue sized for BK=64");
    {
        constexpr int CST = 136;
        f16* Cs = &SMEM[0][0];
        const float qs = (MODE == 3 && bn < 1024) ? QSCALE : 1.f;
        #pragma unroll
        for (int mt = 0; mt < 4; ++mt)
            #pragma unroll
            for (int nt = 0; nt < 4; ++nt) {
                const int lcol = wn + nt * 16 + l15;
                const float bv = bias[bn + lcol];
                #pragma unroll
                for (int i = 0; i < 4; ++i) {
                    const int lrow = wm + mt * 16 + quad * 4 + i;
                    float v = acc[mt][nt][i] + bv;
                    if (MODE == 1) v = v > 0.f ? v : 0.f;
                    Cs[lrow * CST + lcol] = (f16)(v * qs);
                }
            }
        __syncthreads();
        #pragma unroll
        for (int k = 0; k < 8; ++k) {
            const int e = t * 8 + k * 2048;
            const int row = e >> 7, colg = e & 127;
            const f16x8 vv = *(const f16x8*)&Cs[row * CST + colg];
            *(f16x8*)&((f16*)Cout)[(size_t)(bm + row) * N + bn + colg] = vv;
        }
    }
}

// -------- 8-phase counted-vmcnt GEMM, 256x256 tile (T3+T4, proven R16) ------
// ALL 8 half-tiles of kt+1 issued at ph0/ph1 in consumption order:
//   GATE1 (after ph1): vmcnt(8) -- retires A13(kt) (~4 phases old).
//   GATE2 (after ph3): vmcnt(2) -- retires B0-3+A0,A2(kt+1); keeps A13(kt+1)
//                                  in flight across the iteration boundary.
// LDS = 65536 f16 = 128KB: A dbuf [0,32768), B dbuf [32768,65536).
// 512 thr / 8 waves (2M x 4N), BK=64, 1 block/CU.
// ONLY used where the grid packs the machine cleanly (FFN1: 512 blocks =
// 2 rounds). [R17: QKV's 384-block grid = 1.5 rounds REGRESSED +28us.]
__global__ __launch_bounds__(512, 2) void gemm_8ph(const f16* __restrict__ A,
                                                   const f16* __restrict__ B,
                                                   const float* __restrict__ bias,
                                                   f16* __restrict__ Cout,
                                                   int M, int N, int K) {
    __shared__ __align__(16) f16 SM[65536];    // 128KB
    const int t = threadIdx.x;
    const int lane = t & 63, w = t >> 6;
    const int quad = lane >> 4, l15 = lane & 15;
    const int wm = (w >> 2) * 128, wn = (w & 3) * 64;

    const int gx = gridDim.x;                  // N/256
    const int nwg = gx * gridDim.y;
    int lin = blockIdx.y * gx + blockIdx.x;
    lin = (lin & 7) * (nwg >> 3) + (lin >> 3);
    const int bm = (lin / gx) * 256, bn = (lin % gx) * 256;

    f32x4 acc[8][4];
    #pragma unroll
    for (int i = 0; i < 8; ++i)
        #pragma unroll
        for (int j = 0; j < 4; ++j)
            acc[i][j] = (f32x4){0.f, 0.f, 0.f, 0.f};

    const int rt = t >> 3;                     // 0..63
    const int csw = ((t & 7) ^ (rt & 7)) * 8;  // pre-swizzled source chunk
    const f16* Ag = A + (size_t)(bm + rt) * K + csw;
    const f16* Bg = B + (size_t)(bn + rt) * K + csw;
    const int wb8 = (t & ~63) * 8;             // wave-uniform LDS dest base

    // stage one 64-row piece (hh) of A or B for K-tile kt into buf kt&1
    auto issue = [&](int kt, int hh, int isB) {
        const f16* g = (isB ? Bg : Ag) + (size_t)(hh * 64) * K + kt * 64;
        f16* d = &SM[(isB ? 32768 : 0) + (kt & 1) * 16384 + hh * 4096 + wb8];
        async_copy16(g, d);
    };

    auto phase = [&](int cb, int mh, int nh) {
        f16x8 af[4][2], bf[2][2];
        #pragma unroll
        for (int mt = 0; mt < 4; ++mt) {
            const int r = wm + mh * 64 + mt * 16 + l15;
            #pragma unroll
            for (int kp = 0; kp < 2; ++kp) {
                const int slot = (quad + kp * 4) ^ (r & 7);
                af[mt][kp] = *(const f16x8*)&SM[cb * 16384 + r * 64 + slot * 8];
            }
        }
        #pragma unroll
        for (int nf = 0; nf < 2; ++nf) {
            const int r = wn + nh * 32 + nf * 16 + l15;
            #pragma unroll
            for (int kp = 0; kp < 2; ++kp) {
                const int slot = (quad + kp * 4) ^ (r & 7);
                bf[nf][kp] = *(const f16x8*)&SM[32768 + cb * 16384 + r * 64 + slot * 8];
            }
        }
        __builtin_amdgcn_s_setprio(1);
        #pragma unroll
        for (int mt = 0; mt < 4; ++mt)
            #pragma unroll
            for (int nf = 0; nf < 2; ++nf)
                #pragma unroll
                for (int kp = 0; kp < 2; ++kp)
                    acc[mh * 4 + mt][nh * 2 + nf] = __builtin_amdgcn_mfma_f32_16x16x32_f16(
                        af[mt][kp], bf[nf][kp], acc[mh * 4 + mt][nh * 2 + nf], 0, 0, 0);
        __builtin_amdgcn_s_setprio(0);
    };

    // prologue: full tile 0, drained
    #pragma unroll
    for (int hh = 0; hh < 4; ++hh) issue(0, hh, 1);
    #pragma unroll
    for (int hh = 0; hh < 4; ++hh) issue(0, hh, 0);
    asm volatile("s_waitcnt vmcnt(0)" ::: "memory");
    __builtin_amdgcn_s_barrier();
    asm volatile("" ::: "memory");

    const int nkt = K >> 6;
    for (int kt = 0; kt < nkt; ++kt) {
        const int cb = kt & 1;
        const bool pf = (kt + 1 < nkt);
        // ph0: issue first half of tile kt+1 (consumption order: B first, A02)
        if (pf) { issue(kt + 1, 0, 1); issue(kt + 1, 1, 1);
                  issue(kt + 1, 0, 0); issue(kt + 1, 2, 0); }
        phase(cb, 0, 0);
        // ph1: issue second half (B23, A13)
        if (pf) { issue(kt + 1, 2, 1); issue(kt + 1, 3, 1);
                  issue(kt + 1, 1, 0); issue(kt + 1, 3, 0); }
        phase(cb, 0, 1);
        // GATE1: retire A13(kt) (issued iter kt-1 ph1, ~4 phases old)
        if (pf) asm volatile("s_waitcnt vmcnt(8)" ::: "memory");
        else    asm volatile("s_waitcnt vmcnt(0)" ::: "memory");
        __builtin_amdgcn_s_barrier();
        asm volatile("" ::: "memory");
        phase(cb, 1, 0);
        phase(cb, 1, 1);
        // GATE2: retire B0-3 + A0,A2 of (kt+1); keep A13(kt+1) in flight
        if (pf) asm volatile("s_waitcnt vmcnt(2)" ::: "memory");
        __builtin_amdgcn_s_barrier();
        asm volatile("" ::: "memory");
    }

    // epilogue: relu + bias, LDS-staged full-line f16x8 stores (SM is dead;
    // 256x256 f16 = 65536 elems fits exactly)
    #pragma unroll
    for (int am = 0; am < 8; ++am) {
        const int lrow = wm + (am >> 2) * 64 + (am & 3) * 16 + quad * 4;
        #pragma unroll
        for (int an = 0; an < 4; ++an) {
            const int lcol = wn + (an >> 1) * 32 + (an & 1) * 16 + l15;
            const float bv = bias[bn + lcol];
            #pragma unroll
            for (int i = 0; i < 4; ++i) {
                float v = acc[am][an][i] + bv;
                v = v > 0.f ? v : 0.f;
                SM[(lrow + i) * 256 + lcol] = (f16)v;
            }
        }
    }
    __syncthreads();
    #pragma unroll
    for (int k = 0; k < 16; ++k) {
        const int e = t * 8 + k * 4096;
        const int row = e >> 8, col = e & 255;
        *(f16x8*)&Cout[(size_t)(bm + row) * N + bn + col] = *(const f16x8*)&SM[e];
    }
}

// ---------------- Flash attention: P stays in registers ----------------
// [R16 audit: ~77 GFLOP / 91us = 0.84 PF; MfmaUtil 57 + VALU 43 = issue-bound;
//  half the MFMAs are half-rate 16x16x16 -- next lever is a P-layout transform
//  to 16x16x32 PV (cross-lane), deferred as high-risk.]
__global__ __launch_bounds__(256, 4) void attn_kernel(const f16* __restrict__ qkv,
                                                      const f16* __restrict__ vT,
                                                      f16* __restrict__ ctx) {
    const int lin = blockIdx.y * 16 + blockIdx.x;
    const int xcd = lin & 7, idx = lin >> 3;
    const int bh = (idx >> 4) * 8 + xcd;          // xcd = bh % 8
    const int q0 = (idx & 15) * 128;
    const int b = bh >> 4, h = bh & 15;
    const int t = threadIdx.x, lane = t & 63, w = t >> 6;
    const int quad = lane >> 4, l15 = lane & 15;
    const int e = l15 & 7;

    __shared__ __align__(16) f16 KV[4][64 * 64];

    const int srow = t >> 3;
    const int scS = ((t & 7) ^ (srow & 7)) * 8;

    const f16* Kg = qkv + (size_t)(b * S_ + srow) * 3072 + 1024 + h * 64 + scS;
    const f16* Vg = vT + (size_t)(bh * 64 + srow) * S_ + scS;
    const int wb8 = (t & ~63) * 8;

    {
        const f16* g = qkv + (size_t)(b * S_ + q0 + srow) * 3072 + h * 64 + scS;
        f16* dst = &KV[0][wb8];
        #pragma unroll
        for (int c = 0; c < 4; ++c)
            async_copy16(g + (size_t)(c * 32) * 3072, dst + c * 2048);
    }
    __syncthreads();

    f16x8 qf[2][2];
    #pragma unroll
    for (int band = 0; band < 2; ++band) {
        const int qr = w * 32 + band * 16 + l15;
        const int qx = qr & 7;
        qf[band][0] = *(const f16x8*)&KV[0][qr * 64 + ((quad) ^ qx) * 8];
        qf[band][1] = *(const f16x8*)&KV[0][qr * 64 + ((quad + 4) ^ qx) * 8];
    }
    __syncthreads();

    {
        async_copy16(Kg, &KV[0][wb8]);
        async_copy16(Kg + (size_t)32 * 3072, &KV[0][2048 + wb8]);
        async_copy16(Vg, &KV[2][wb8]);
        async_copy16(Vg + (size_t)32 * S_, &KV[2][2048 + wb8]);
    }
    __syncthreads();

    const int kbase0 = l15 * 64 + ((quad) ^ e) * 8;
    const int kbase1 = l15 * 64 + ((quad + 4) ^ e) * 8;
    int vbase[4];
    #pragma unroll
    for (int kb = 0; kb < 4; ++kb)
        vbase[kb] = l15 * 64 + (((kb * 2) + (quad >> 1)) ^ e) * 8 + (quad & 1) * 4;

    const f16 one = (f16)1.f;
    const f16x4 ones4 = { one, one, one, one };
    const f32x4 einit = (f32x4){EXPC, EXPC, EXPC, EXPC};

    f32x4 o[2][4];
    f32x4 accl[2];
    #pragma unroll
    for (int band = 0; band < 2; ++band) {
        accl[band] = (f32x4){0.f, 0.f, 0.f, 0.f};
        #pragma unroll
        for (int dt = 0; dt < 4; ++dt) o[band][dt] = (f32x4){0.f, 0.f, 0.f, 0.f};
    }

    for (int j = 0; j < 32; ++j) {
        const int cur = j & 1;
        if (j + 1 < 32) {
            const int nxt = cur ^ 1;
            const f16* kg = Kg + (size_t)(j + 1) * 64 * 3072;
            async_copy16(kg, &KV[nxt][wb8]);
            async_copy16(kg + (size_t)32 * 3072, &KV[nxt][2048 + wb8]);
            const f16* vg = Vg + (j + 1) * 64;
            async_copy16(vg, &KV[2 + nxt][wb8]);
            async_copy16(vg + (size_t)32 * S_, &KV[2 + nxt][2048 + wb8]);
        }

        f16x4 pa[2][4];
        #pragma unroll
        for (int band = 0; band < 2; ++band) {
            #pragma unroll
            for (int nt = 0; nt < 4; ++nt) {
                const f16x8 kf0 = *(const f16x8*)&KV[cur][kbase0 + nt * 1024];
                const f16x8 kf1 = *(const f16x8*)&KV[cur][kbase1 + nt * 1024];
                f32x4 s = einit;
                s = __builtin_amdgcn_mfma_f32_16x16x32_f16(kf0, qf[band][0], s, 0, 0, 0);
                s = __builtin_amdgcn_mfma_f32_16x16x32_f16(kf1, qf[band][1], s, 0, 0, 0);
                const f16x2 lo = pk_cvt(__builtin_amdgcn_exp2f(s[0]),
                                        __builtin_amdgcn_exp2f(s[1]));
                const f16x2 hi = pk_cvt(__builtin_amdgcn_exp2f(s[2]),
                                        __builtin_amdgcn_exp2f(s[3]));
                const f16x4 p = __builtin_shufflevector(lo, hi, 0, 1, 2, 3);
                pa[band][nt] = p;
                accl[band] = __builtin_amdgcn_mfma_f32_16x16x16f16(p, ones4, accl[band], 0, 0, 0);
            }
        }

        __builtin_amdgcn_s_setprio(1);
        #pragma unroll
        for (int dt = 0; dt < 4; ++dt) {
            #pragma unroll
            for (int kb = 0; kb < 4; ++kb) {
                const f16x4 vf = *(const f16x4*)&KV[2 + cur][vbase[kb] + dt * 1024];
                o[0][dt] = __builtin_amdgcn_mfma_f32_16x16x16f16(pa[0][kb], vf, o[0][dt], 0, 0, 0);
                o[1][dt] = __builtin_amdgcn_mfma_f32_16x16x16f16(pa[1][kb], vf, o[1][dt], 0, 0, 0);
            }
        }
        __builtin_amdgcn_s_setprio(0);

        __syncthreads();
    }

    #pragma unroll
    for (int band = 0; band < 2; ++band) {
        float linv[4];
        #pragma unroll
        for (int i = 0; i < 4; ++i) linv[i] = 1.f / accl[band][i];
        #pragma unroll
        for (int dt = 0; dt < 4; ++dt)
            #pragma unroll
            for (int i = 0; i < 4; ++i) {
                const int r = q0 + w * 32 + band * 16 + quad * 4 + i;
                const int d = dt * 16 + l15;
                ctx[(size_t)(b * S_ + r) * DM + h * 64 + d] = (f16)(o[band][dt][i] * linv[i]);
            }
    }
}

// ---------------- launch ----------------
extern "C" void kernel_launch(void* const* d_in, const int* in_sizes, int n_in,
                              void* d_out, int out_size, void* d_ws, size_t ws_size,
                              hipStream_t stream) {
    const float* x    = (const float*)d_in[0];
    const float* wq   = (const float*)d_in[2];
    const float* bq   = (const float*)d_in[3];
    const float* wk   = (const float*)d_in[4];
    const float* bk   = (const float*)d_in[5];
    const float* wv   = (const float*)d_in[6];
    const float* bv   = (const float*)d_in[7];
    const float* wo   = (const float*)d_in[8];
    const float* bo   = (const float*)d_in[9];
    const float* w1   = (const float*)d_in[10];
    const float* b1   = (const float*)d_in[11];
    const float* w2   = (const float*)d_in[12];
    const float* b2   = (const float*)d_in[13];
    const float* ln1a = (const float*)d_in[14];
    const float* ln1b = (const float*)d_in[15];
    const float* ln2a = (const float*)d_in[16];
    const float* ln2b = (const float*)d_in[17];
    float* out = (float*)d_out;

    char* ws = (char*)d_ws;
    size_t off = 0;
    auto alloc = [&](size_t bytes) -> void* {
        void* p = ws + off;
        off += (bytes + 255) & ~(size_t)255;
        return p;
    };
    f16* wqkvb  = (f16*)alloc((size_t)3072 * 1024 * 2);
    f16* wob    = (f16*)alloc((size_t)1024 * 1024 * 2);
    f16* w1b    = (f16*)alloc((size_t)4096 * 1024 * 2);
    f16* w2b    = (f16*)alloc((size_t)1024 * 4096 * 2);
    float* bqkv = (float*)alloc((size_t)3072 * 4);
    f16* hbuf   = (f16*)alloc((size_t)8192 * 1024 * 2);
    f16* qkvb   = (f16*)alloc((size_t)8192 * 3072 * 2);
    f16* vTb    = (f16*)alloc((size_t)64 * 64 * 2048 * 2);
    f16* ctxb   = (f16*)alloc((size_t)8192 * 1024 * 2);
    f16* ffn1b  = qkvb;  // overlay: qkv (48MB) + vT (16MB) region, both dead by FFN1

    const int M = B_ * S_;  // 8192

    convert_all<<<12300 + M, 256, 0, stream>>>(wq, wk, wv, wo, w1, w2, bq, bk, bv,
                                               wqkvb, wob, w1b, w2b, bqkv,
                                               x, hbuf, ln1a, ln1b);
    gemm_bt<3, 64><<<dim3(3072 / 128, M / 128), 256, 0, stream>>>(hbuf, wqkvb, bqkv, nullptr, qkvb, vTb, M, 3072, 1024);
    attn_kernel<<<dim3(16, 64), 256, 0, stream>>>(qkvb, vTb, ctxb);
    gemm_bt<2, 64><<<dim3(1024 / 128, M / 128), 256, 0, stream>>>(ctxb, wob, bo, x, out, nullptr, M, 1024, 1024);
    ln_kernel<<<M, 256, 0, stream>>>(out, hbuf, ln2a, ln2b);
    // FFN1: 8-phase counted-vmcnt 256x256 kernel (relu f16 out)
    gemm_8ph<<<dim3(4096 / 256, M / 256), 512, 0, stream>>>(hbuf, w1b, b1, ffn1b, M, 4096, 1024);
    gemm_bt<2, 64><<<dim3(1024 / 128, M / 128), 256, 0, stream>>>(ffn1b, w2b, b2, out, out, nullptr, M, 1024, 4096);
}